// Round 4
// baseline (1326.403 us; speedup 1.0000x reference)
//
#include <hip/hip_runtime.h>

#define NN 50000
#define EE 800000
#define DD 128
#define RR 8
#define KSTACK 1152   // (RR+1)*DD stacked K
#define NR2 (NN * RR) // 400000
#define RPB 16        // dst rows per fused block
#define ACCW 1156     // fp32 words per LDS acc row (1152 + 4 pad)

typedef __attribute__((ext_vector_type(8))) short bf16x8;
typedef __attribute__((ext_vector_type(4))) float f32x4;

__device__ inline float bf2f(ushort u) {
    union { uint i; float f; } v; v.i = ((uint)u) << 16; return v.f;
}
__device__ inline ushort f2bf(float f) {
    uint b = __float_as_uint(f);
    uint r = (b + 0x7fffu + ((b >> 16) & 1u)) >> 16;
    return (ushort)r;
}

// Both layers' stacked transposed weights in one launch (blockIdx.y picks layer).
// wT[o][k]: k<1024 -> sum_b comp[r,b]*basis[b,i,o] (r=k>>7, i=k&127); k>=1024 -> root[k-1024][o].
__global__ void k_build_w2(const float* __restrict__ b0, const float* __restrict__ c0,
                           const float* __restrict__ r0, const float* __restrict__ b1,
                           const float* __restrict__ c1, const float* __restrict__ r1,
                           ushort* __restrict__ w0, ushort* __restrict__ w1) {
    int idx = blockIdx.x * 256 + threadIdx.x;
    if (idx >= DD * KSTACK) return;
    const float* basis = blockIdx.y ? b1 : b0;
    const float* comp  = blockIdx.y ? c1 : c0;
    const float* root  = blockIdx.y ? r1 : r0;
    ushort* wT         = blockIdx.y ? w1 : w0;
    int o = idx / KSTACK;
    int k = idx % KSTACK;
    float val;
    if (k < RR * DD) {
        int r = k >> 7, i = k & 127;
        float s = 0.f;
        #pragma unroll
        for (int b = 0; b < 8; ++b) s += comp[r * 8 + b] * basis[(b * 128 + i) * 128 + o];
        val = s;
    } else {
        val = root[(k - RR * DD) * 128 + o];
    }
    wT[(size_t)o * KSTACK + k] = f2bf(val);
}

__global__ void k_cvt_bf16(const float* __restrict__ x, ushort* __restrict__ xb, int n4) {
    int i = blockIdx.x * 256 + threadIdx.x;
    if (i < n4) {
        float4 v = ((const float4*)x)[i];
        uint2 p;
        p.x = (uint)f2bf(v.x) | ((uint)f2bf(v.y) << 16);
        p.y = (uint)f2bf(v.z) | ((uint)f2bf(v.w) << 16);
        ((uint2*)xb)[i] = p;
    }
}

__global__ void k_hist(const int* __restrict__ ei, const int* __restrict__ et,
                       int* __restrict__ deg_dr, int* __restrict__ row_cnt) {
    int e = blockIdx.x * 256 + threadIdx.x;
    if (e < EE) {
        int d = ei[EE + e], t = et[e];
        atomicAdd(&deg_dr[d * RR + t], 1);
        atomicAdd(&row_cnt[d], 1);
    }
}

__global__ void k_scan1(const int* __restrict__ cnt, int* __restrict__ bsum, int n) {
    __shared__ int s[256];
    int t = threadIdx.x;
    int i = blockIdx.x * 256 + t;
    s[t] = (i < n) ? cnt[i] : 0;
    __syncthreads();
    for (int o = 128; o > 0; o >>= 1) {
        if (t < o) s[t] += s[t + o];
        __syncthreads();
    }
    if (t == 0) bsum[blockIdx.x] = s[0];
}

__global__ void k_scan2(int* __restrict__ bsum, int nb) {
    __shared__ int s[256];
    int t = threadIdx.x;
    int v = (t < nb) ? bsum[t] : 0;
    s[t] = v;
    __syncthreads();
    for (int o = 1; o < 256; o <<= 1) {
        int u = (t >= o) ? s[t - o] : 0;
        __syncthreads();
        s[t] += u;
        __syncthreads();
    }
    if (t < nb) bsum[t] = s[t] - v;   // exclusive
}

__global__ void k_scan3(const int* __restrict__ cnt, const int* __restrict__ boff,
                        int* __restrict__ ptr, int n) {
    __shared__ int s[256];
    int t = threadIdx.x;
    int i = blockIdx.x * 256 + t;
    int v = (i < n) ? cnt[i] : 0;
    s[t] = v;
    __syncthreads();
    for (int o = 1; o < 256; o <<= 1) {
        int u = (t >= o) ? s[t - o] : 0;
        __syncthreads();
        s[t] += u;
        __syncthreads();
    }
    if (i < n) ptr[i + 1] = boff[blockIdx.x] + s[t];
    if (i == 0) ptr[0] = 0;
}

// Per edge at dst-sorted position: {key = src*8+rel, w = 1/deg(dst,rel)}.
__global__ void k_scatter(const int* __restrict__ ei, const int* __restrict__ et,
                          const int* __restrict__ row_ptr, const int* __restrict__ deg_dr,
                          int* __restrict__ cursor, int2* __restrict__ ekw) {
    int e = blockIdx.x * 256 + threadIdx.x;
    if (e < EE) {
        int s = ei[e], d = ei[EE + e], t = et[e];
        int p = row_ptr[d] + atomicAdd(&cursor[d], 1);
        int2 pk;
        pk.x = (s << 3) | t;
        pk.y = __float_as_int(1.f / (float)deg_dr[d * RR + t]);
        ekw[p] = pk;
    }
}

// Fused layer. Block = 16 dst rows, 256 threads (4 waves), 74KB LDS -> 2 blocks/CU.
// Phase 1: wave owns 4 rows; flat per-row edge loop, unroll 4; slot-routed
//          accumulation via fire-and-forget LDS float atomics (ds_add_f32).
// Phase 2: 36 K-step MFMA GEMM [16 x 1152] @ [1152 x 128]; A from LDS fp32
//          (cvt_pk to bf16), B streamed from L2-resident wT; fused bias(+ReLU).
__global__ void __launch_bounds__(256, 2) k_fused2(
        const ushort* __restrict__ in, const int* __restrict__ rp,
        const int2* __restrict__ ekw, const ushort* __restrict__ BT,
        const float* __restrict__ bias, ushort* __restrict__ hout,
        float* __restrict__ fout) {
    __shared__ float acc[RPB * ACCW];   // 73,984 B
    int tid = threadIdx.x;
    int wid = tid >> 6, lane = tid & 63;
    int blockrow = blockIdx.x * RPB;

    float4 z4 = {0.f, 0.f, 0.f, 0.f};
    for (int i = tid; i < RPB * ACCW / 4; i += 256)
        ((float4*)acc)[i] = z4;
    __syncthreads();

    int l2 = lane << 1;
    for (int rr = 0; rr < 4; ++rr) {
        int lr = (wid << 2) + rr;
        int n = blockrow + lr;
        float* arow = acc + lr * ACCW;
        int p  = __builtin_amdgcn_readfirstlane(rp[n]);
        int p1 = __builtin_amdgcn_readfirstlane(rp[n + 1]);
        for (; p + 4 <= p1; p += 4) {
            int2 e0 = ekw[p], e1 = ekw[p + 1], e2 = ekw[p + 2], e3 = ekw[p + 3];
            uint u0 = *(const uint*)(in + (size_t)(e0.x >> 3) * DD + l2);
            uint u1 = *(const uint*)(in + (size_t)(e1.x >> 3) * DD + l2);
            uint u2 = *(const uint*)(in + (size_t)(e2.x >> 3) * DD + l2);
            uint u3 = *(const uint*)(in + (size_t)(e3.x >> 3) * DD + l2);
            float w0 = __int_as_float(e0.y), w1 = __int_as_float(e1.y);
            float w2 = __int_as_float(e2.y), w3 = __int_as_float(e3.y);
            atomicAdd(&arow[(e0.x & 7) * DD + l2],     w0 * bf2f((ushort)(u0 & 0xffffu)));
            atomicAdd(&arow[(e0.x & 7) * DD + l2 + 1], w0 * bf2f((ushort)(u0 >> 16)));
            atomicAdd(&arow[(e1.x & 7) * DD + l2],     w1 * bf2f((ushort)(u1 & 0xffffu)));
            atomicAdd(&arow[(e1.x & 7) * DD + l2 + 1], w1 * bf2f((ushort)(u1 >> 16)));
            atomicAdd(&arow[(e2.x & 7) * DD + l2],     w2 * bf2f((ushort)(u2 & 0xffffu)));
            atomicAdd(&arow[(e2.x & 7) * DD + l2 + 1], w2 * bf2f((ushort)(u2 >> 16)));
            atomicAdd(&arow[(e3.x & 7) * DD + l2],     w3 * bf2f((ushort)(u3 & 0xffffu)));
            atomicAdd(&arow[(e3.x & 7) * DD + l2 + 1], w3 * bf2f((ushort)(u3 >> 16)));
        }
        for (; p < p1; ++p) {
            int2 e = ekw[p];
            uint u = *(const uint*)(in + (size_t)(e.x >> 3) * DD + l2);
            float w = __int_as_float(e.y);
            atomicAdd(&arow[(e.x & 7) * DD + l2],     w * bf2f((ushort)(u & 0xffffu)));
            atomicAdd(&arow[(e.x & 7) * DD + l2 + 1], w * bf2f((ushort)(u >> 16)));
        }
        // self (root) slot — wave-owned row, plain LDS store
        uint su = *(const uint*)(in + (size_t)n * DD + l2);
        arow[RR * DD + l2]     = bf2f((ushort)(su & 0xffffu));
        arow[RR * DD + l2 + 1] = bf2f((ushort)(su >> 16));
    }
    __syncthreads();

    // Phase 2
    int rlo = lane & 15, q = lane >> 4, khi = q * 8;
    int colbase = wid * 32;
    const float*  ap  = acc + rlo * ACCW + khi;
    const ushort* bp0 = BT + (size_t)(colbase + rlo) * KSTACK + khi;
    const ushort* bp1 = bp0 + (size_t)16 * KSTACK;
    f32x4 c0 = {0.f, 0.f, 0.f, 0.f}, c1 = {0.f, 0.f, 0.f, 0.f};
    #pragma unroll 4
    for (int kk = 0; kk < KSTACK / 32; ++kk) {
        int ko = kk * 32;
        float4 fa0 = *(const float4*)(ap + ko);
        float4 fa1 = *(const float4*)(ap + ko + 4);
        union { bf16x8 v; uint u[4]; } A;
        asm("v_cvt_pk_bf16_f32 %0, %1, %2" : "=v"(A.u[0]) : "v"(fa0.x), "v"(fa0.y));
        asm("v_cvt_pk_bf16_f32 %0, %1, %2" : "=v"(A.u[1]) : "v"(fa0.z), "v"(fa0.w));
        asm("v_cvt_pk_bf16_f32 %0, %1, %2" : "=v"(A.u[2]) : "v"(fa1.x), "v"(fa1.y));
        asm("v_cvt_pk_bf16_f32 %0, %1, %2" : "=v"(A.u[3]) : "v"(fa1.z), "v"(fa1.w));
        bf16x8 b0 = *(const bf16x8*)(bp0 + ko);
        bf16x8 b1 = *(const bf16x8*)(bp1 + ko);
        c0 = __builtin_amdgcn_mfma_f32_16x16x32_bf16(A.v, b0, c0, 0, 0, 0);
        c1 = __builtin_amdgcn_mfma_f32_16x16x32_bf16(A.v, b1, c1, 0, 0, 0);
    }
    int col0 = colbase + rlo, col1 = col0 + 16;
    float bv0 = bias[col0], bv1 = bias[col1];
    #pragma unroll
    for (int rg = 0; rg < 4; ++rg) {
        int row = blockrow + q * 4 + rg;   // grid is exact: 3125*16 == NN
        float v0 = c0[rg] + bv0, v1 = c1[rg] + bv1;
        if (hout) {
            v0 = fmaxf(v0, 0.f); v1 = fmaxf(v1, 0.f);
            hout[(size_t)row * DD + col0] = f2bf(v0);
            hout[(size_t)row * DD + col1] = f2bf(v1);
        } else {
            fout[(size_t)row * DD + col0] = v0;
            fout[(size_t)row * DD + col1] = v1;
        }
    }
}

extern "C" void kernel_launch(void* const* d_in, const int* in_sizes, int n_in,
                              void* d_out, int out_size, void* d_ws, size_t ws_size,
                              hipStream_t stream) {
    const float* x      = (const float*)d_in[0];
    const int*   ei     = (const int*)d_in[1];
    const int*   et     = (const int*)d_in[2];
    const float* basis0 = (const float*)d_in[3];
    const float* comp0  = (const float*)d_in[4];
    const float* root0  = (const float*)d_in[5];
    const float* bias0  = (const float*)d_in[6];
    const float* basis1 = (const float*)d_in[7];
    const float* comp1  = (const float*)d_in[8];
    const float* root1  = (const float*)d_in[9];
    const float* bias1  = (const float*)d_in[10];
    float* out = (float*)d_out;

    char* ws = (char*)d_ws;
    size_t off = 0;
    auto alloc = [&](size_t bytes) -> void* {
        void* p = ws + off;
        off += (bytes + 255) & ~(size_t)255;
        return p;
    };
    int*    deg_dr  = (int*)alloc((size_t)NR2 * 4);
    int*    row_cnt = (int*)alloc((size_t)NN * 4);
    int*    cursor  = (int*)alloc((size_t)NN * 4);
    size_t zero_bytes = off;
    int*    row_ptr = (int*)alloc((size_t)(NN + 1) * 4);
    int*    bsum    = (int*)alloc(256 * 4);
    int2*   ekw     = (int2*)alloc((size_t)EE * 8);
    ushort* wT0     = (ushort*)alloc((size_t)DD * KSTACK * 2);
    ushort* wT1     = (ushort*)alloc((size_t)DD * KSTACK * 2);
    ushort* xb      = (ushort*)alloc((size_t)NN * DD * 2);
    ushort* h       = (ushort*)alloc((size_t)NN * DD * 2);
    if (off > ws_size) return;

    hipMemsetAsync(d_ws, 0, zero_bytes, stream);

    dim3 wgrid(576, 2);
    k_build_w2<<<wgrid, 256, 0, stream>>>(basis0, comp0, root0, basis1, comp1, root1, wT0, wT1);
    k_cvt_bf16<<<6250, 256, 0, stream>>>(x, xb, NN * DD / 4);
    k_hist<<<3125, 256, 0, stream>>>(ei, et, deg_dr, row_cnt);
    k_scan1<<<196, 256, 0, stream>>>(row_cnt, bsum, NN);
    k_scan2<<<1, 256, 0, stream>>>(bsum, 196);
    k_scan3<<<196, 256, 0, stream>>>(row_cnt, bsum, row_ptr, NN);
    k_scatter<<<3125, 256, 0, stream>>>(ei, et, row_ptr, deg_dr, cursor, ekw);

    int fblocks = NN / RPB;   // 3125, exact
    k_fused2<<<fblocks, 256, 0, stream>>>(xb, row_ptr, ekw, wT0, bias0, h, nullptr);
    k_fused2<<<fblocks, 256, 0, stream>>>(h, row_ptr, ekw, wT1, bias1, nullptr, out);
}

// Round 5
// 347.449 us; speedup vs baseline: 3.8175x; 3.8175x over previous
//
#include <hip/hip_runtime.h>

#define NN 50000
#define EE 800000
#define DD 128
#define RR 8
#define KSTACK 1152   // (RR+1)*DD stacked K
#define NR2 (NN * RR) // 400000
#define RPB 32        // dst rows per fused block
#define LDSROW 1160   // bf16 elems per A-tile row (1152 + 8 pad)

typedef __attribute__((ext_vector_type(8))) short bf16x8;
typedef __attribute__((ext_vector_type(4))) float f32x4;

__device__ inline float bf2f(ushort u) {
    union { uint i; float f; } v; v.i = ((uint)u) << 16; return v.f;
}
__device__ inline ushort f2bf(float f) {
    uint b = __float_as_uint(f);
    uint r = (b + 0x7fffu + ((b >> 16) & 1u)) >> 16;
    return (ushort)r;
}

// Both layers' stacked transposed weights: wT[o][k].
__global__ void k_build_w2(const float* __restrict__ b0, const float* __restrict__ c0,
                           const float* __restrict__ r0, const float* __restrict__ b1,
                           const float* __restrict__ c1, const float* __restrict__ r1,
                           ushort* __restrict__ w0, ushort* __restrict__ w1) {
    int idx = blockIdx.x * 256 + threadIdx.x;
    if (idx >= DD * KSTACK) return;
    const float* basis = blockIdx.y ? b1 : b0;
    const float* comp  = blockIdx.y ? c1 : c0;
    const float* root  = blockIdx.y ? r1 : r0;
    ushort* wT         = blockIdx.y ? w1 : w0;
    int o = idx / KSTACK;
    int k = idx % KSTACK;
    float val;
    if (k < RR * DD) {
        int r = k >> 7, i = k & 127;
        float s = 0.f;
        #pragma unroll
        for (int b = 0; b < 8; ++b) s += comp[r * 8 + b] * basis[(b * 128 + i) * 128 + o];
        val = s;
    } else {
        val = root[(k - RR * DD) * 128 + o];
    }
    wT[(size_t)o * KSTACK + k] = f2bf(val);
}

__global__ void k_cvt_bf16(const float* __restrict__ x, ushort* __restrict__ xb, int n4) {
    int i = blockIdx.x * 256 + threadIdx.x;
    if (i < n4) {
        float4 v = ((const float4*)x)[i];
        uint2 p;
        p.x = (uint)f2bf(v.x) | ((uint)f2bf(v.y) << 16);
        p.y = (uint)f2bf(v.z) | ((uint)f2bf(v.w) << 16);
        ((uint2*)xb)[i] = p;
    }
}

__global__ void k_hist(const int* __restrict__ ei, const int* __restrict__ et,
                       int* __restrict__ deg_dr) {
    int e = blockIdx.x * 256 + threadIdx.x;
    if (e < EE) atomicAdd(&deg_dr[ei[EE + e] * RR + et[e]], 1);
}

// Row degree = sum of 8 consecutive deg_dr entries (computed inline, no row_cnt buffer).
__device__ inline int rowdeg(const int* __restrict__ deg_dr, int n) {
    int4 a = ((const int4*)deg_dr)[2 * n];
    int4 b = ((const int4*)deg_dr)[2 * n + 1];
    return a.x + a.y + a.z + a.w + b.x + b.y + b.z + b.w;
}

__global__ void k_scan1(const int* __restrict__ deg_dr, int* __restrict__ bsum, int n) {
    __shared__ int s[256];
    int t = threadIdx.x;
    int i = blockIdx.x * 256 + t;
    s[t] = (i < n) ? rowdeg(deg_dr, i) : 0;
    __syncthreads();
    for (int o = 128; o > 0; o >>= 1) {
        if (t < o) s[t] += s[t + o];
        __syncthreads();
    }
    if (t == 0) bsum[blockIdx.x] = s[0];
}

__global__ void k_scan2(int* __restrict__ bsum, int nb) {
    __shared__ int s[256];
    int t = threadIdx.x;
    int v = (t < nb) ? bsum[t] : 0;
    s[t] = v;
    __syncthreads();
    for (int o = 1; o < 256; o <<= 1) {
        int u = (t >= o) ? s[t - o] : 0;
        __syncthreads();
        s[t] += u;
        __syncthreads();
    }
    if (t < nb) bsum[t] = s[t] - v;   // exclusive
}

__global__ void k_scan3(const int* __restrict__ deg_dr, const int* __restrict__ boff,
                        int* __restrict__ ptr, int n) {
    __shared__ int s[256];
    int t = threadIdx.x;
    int i = blockIdx.x * 256 + t;
    int v = (i < n) ? rowdeg(deg_dr, i) : 0;
    s[t] = v;
    __syncthreads();
    for (int o = 1; o < 256; o <<= 1) {
        int u = (t >= o) ? s[t - o] : 0;
        __syncthreads();
        s[t] += u;
        __syncthreads();
    }
    if (i < n) ptr[i + 1] = boff[blockIdx.x] + s[t];
    if (i == 0) ptr[0] = 0;
}

// Per edge at (dst,rel)-sorted position: {key = src*8+rel, w = 1/deg(dst,rel)}.
// Sorted-by-rel within each dst row because position = row_ptr[d] + cursor, and
// we order by rel via the composite index: use rel-major cursor per row.
__global__ void k_scatter(const int* __restrict__ ei, const int* __restrict__ et,
                          const int* __restrict__ row_ptr, const int* __restrict__ deg_dr,
                          int* __restrict__ cursor, int2* __restrict__ ekw) {
    int e = blockIdx.x * 256 + threadIdx.x;
    if (e < EE) {
        int s = ei[e], d = ei[EE + e], t = et[e];
        // offset of relation t within row d = sum of deg_dr[d*8 + 0..t-1]
        int4 a = ((const int4*)deg_dr)[2 * d];
        int4 b = ((const int4*)deg_dr)[2 * d + 1];
        int pre = 0;
        pre += (t > 0) ? a.x : 0; pre += (t > 1) ? a.y : 0;
        pre += (t > 2) ? a.z : 0; pre += (t > 3) ? a.w : 0;
        pre += (t > 4) ? b.x : 0; pre += (t > 5) ? b.y : 0;
        pre += (t > 6) ? b.z : 0;
        int deg = (t == 0) ? a.x : (t == 1) ? a.y : (t == 2) ? a.z : (t == 3) ? a.w
                : (t == 4) ? b.x : (t == 5) ? b.y : (t == 6) ? b.z : b.w;
        int p = row_ptr[d] + pre + atomicAdd(&cursor[d * RR + t], 1);
        int2 pk;
        pk.x = (s << 3) | t;
        pk.y = __float_as_int(1.f / (float)deg);
        ekw[p] = pk;
    }
}

// Fused layer. Block = 32 dst rows, 512 threads (8 waves), 74KB LDS -> 2 blocks/CU.
// Phase 1: wave owns 4 rows serially; flat rel-sorted edge loop, unroll 4,
//          register run-accumulation + unconditional overwrite-flush to bf16 A-tile
//          (last write of each rel-run holds the full f32 sum). No atomics, no branches.
// Phase 2: 36 K-step MFMA GEMM [32 x 1152] @ [1152 x 128]; A from LDS bf16,
//          B streamed from L2-resident wT; fused bias (+ReLU).
__global__ void __launch_bounds__(512, 4) k_fused3(
        const ushort* __restrict__ in, const int* __restrict__ rp,
        const int2* __restrict__ ekw, const ushort* __restrict__ BT,
        const float* __restrict__ bias, ushort* __restrict__ hout,
        float* __restrict__ fout) {
    __shared__ ushort at[RPB * LDSROW];   // 74,240 B
    int tid = threadIdx.x, wid = tid >> 6, lane = tid & 63;
    int blockrow = blockIdx.x * RPB;
    int l2 = lane << 1;

    {
        uint4 z = {0u, 0u, 0u, 0u};
        for (int i = tid; i < RPB * LDSROW / 8; i += 512) ((uint4*)at)[i] = z;
    }
    __syncthreads();

    const ushort* inl = in + l2;
    for (int rr = 0; rr < 4; ++rr) {
        int lr = (wid << 2) + rr;
        int n = blockrow + lr;
        if (n >= NN) break;
        ushort* arow = at + lr * LDSROW;
        int p  = __builtin_amdgcn_readfirstlane(rp[n]);
        int p1 = __builtin_amdgcn_readfirstlane(rp[n + 1]);
        float a0 = 0.f, a1 = 0.f;
        int prev = -1;
        for (; p + 4 <= p1; p += 4) {
            int2 e0 = ekw[p], e1 = ekw[p + 1], e2 = ekw[p + 2], e3 = ekw[p + 3];
            uint u0 = *(const uint*)(inl + ((size_t)(e0.x >> 3)) * DD);
            uint u1 = *(const uint*)(inl + ((size_t)(e1.x >> 3)) * DD);
            uint u2 = *(const uint*)(inl + ((size_t)(e2.x >> 3)) * DD);
            uint u3 = *(const uint*)(inl + ((size_t)(e3.x >> 3)) * DD);
            #pragma unroll
            for (int j = 0; j < 4; ++j) {
                int key = (j == 0) ? e0.x : (j == 1) ? e1.x : (j == 2) ? e2.x : e3.x;
                uint u  = (j == 0) ? u0   : (j == 1) ? u1   : (j == 2) ? u2   : u3;
                float w = __int_as_float((j == 0) ? e0.y : (j == 1) ? e1.y
                                       : (j == 2) ? e2.y : e3.y);
                int rel = key & 7;
                bool same = (rel == prev);
                a0 = same ? a0 : 0.f;
                a1 = same ? a1 : 0.f;
                a0 += w * bf2f((ushort)(u & 0xffffu));
                a1 += w * bf2f((ushort)(u >> 16));
                uint pk;
                asm("v_cvt_pk_bf16_f32 %0, %1, %2" : "=v"(pk) : "v"(a0), "v"(a1));
                *(uint*)(arow + rel * DD + l2) = pk;
                prev = rel;
            }
        }
        for (; p < p1; ++p) {
            int2 e = ekw[p];
            uint u = *(const uint*)(inl + ((size_t)(e.x >> 3)) * DD);
            float w = __int_as_float(e.y);
            int rel = e.x & 7;
            bool same = (rel == prev);
            a0 = same ? a0 : 0.f;
            a1 = same ? a1 : 0.f;
            a0 += w * bf2f((ushort)(u & 0xffffu));
            a1 += w * bf2f((ushort)(u >> 16));
            uint pk;
            asm("v_cvt_pk_bf16_f32 %0, %1, %2" : "=v"(pk) : "v"(a0), "v"(a1));
            *(uint*)(arow + rel * DD + l2) = pk;
            prev = rel;
        }
        // self (root) slot
        *(uint*)(arow + RR * DD + l2) = *(const uint*)(inl + (size_t)n * DD);
    }
    __syncthreads();

    // Phase 2: wave wid covers cols [wid*16, wid*16+16), rows 0..31 (2 fragments).
    int rlo = lane & 15, q = lane >> 4, khi = q << 3;
    int colbase = wid << 4;
    const ushort* bp  = BT + (size_t)(colbase + rlo) * KSTACK + khi;
    const ushort* a0p = at + rlo * LDSROW + khi;
    const ushort* a1p = at + (16 + rlo) * LDSROW + khi;
    f32x4 c0 = {0.f, 0.f, 0.f, 0.f}, c1 = {0.f, 0.f, 0.f, 0.f};
    #pragma unroll 4
    for (int kk = 0; kk < KSTACK / 32; ++kk) {
        int ko = kk * 32;
        bf16x8 b  = *(const bf16x8*)(bp + ko);
        bf16x8 a0 = *(const bf16x8*)(a0p + ko);
        bf16x8 a1 = *(const bf16x8*)(a1p + ko);
        c0 = __builtin_amdgcn_mfma_f32_16x16x32_bf16(a0, b, c0, 0, 0, 0);
        c1 = __builtin_amdgcn_mfma_f32_16x16x32_bf16(a1, b, c1, 0, 0, 0);
    }
    int col = colbase + rlo;
    float bv = bias[col];
    int rowoff = q << 2;
    #pragma unroll
    for (int f = 0; f < 2; ++f) {
        f32x4 cv = f ? c1 : c0;
        #pragma unroll
        for (int rg = 0; rg < 4; ++rg) {
            int row = blockrow + f * 16 + rowoff + rg;
            if (row < NN) {
                float v = cv[rg] + bv;
                if (hout) {
                    v = fmaxf(v, 0.f);
                    hout[(size_t)row * DD + col] = f2bf(v);
                } else {
                    fout[(size_t)row * DD + col] = v;
                }
            }
        }
    }
}

extern "C" void kernel_launch(void* const* d_in, const int* in_sizes, int n_in,
                              void* d_out, int out_size, void* d_ws, size_t ws_size,
                              hipStream_t stream) {
    const float* x      = (const float*)d_in[0];
    const int*   ei     = (const int*)d_in[1];
    const int*   et     = (const int*)d_in[2];
    const float* basis0 = (const float*)d_in[3];
    const float* comp0  = (const float*)d_in[4];
    const float* root0  = (const float*)d_in[5];
    const float* bias0  = (const float*)d_in[6];
    const float* basis1 = (const float*)d_in[7];
    const float* comp1  = (const float*)d_in[8];
    const float* root1  = (const float*)d_in[9];
    const float* bias1  = (const float*)d_in[10];
    float* out = (float*)d_out;

    char* ws = (char*)d_ws;
    size_t off = 0;
    auto alloc = [&](size_t bytes) -> void* {
        void* p = ws + off;
        off += (bytes + 255) & ~(size_t)255;
        return p;
    };
    int*    deg_dr  = (int*)alloc((size_t)NR2 * 4);
    int*    cursor  = (int*)alloc((size_t)NR2 * 4);
    size_t zero_bytes = off;
    int*    row_ptr = (int*)alloc((size_t)(NN + 1) * 4);
    int*    bsum    = (int*)alloc(256 * 4);
    int2*   ekw     = (int2*)alloc((size_t)EE * 8);
    ushort* wT0     = (ushort*)alloc((size_t)DD * KSTACK * 2);
    ushort* wT1     = (ushort*)alloc((size_t)DD * KSTACK * 2);
    ushort* xb      = (ushort*)alloc((size_t)NN * DD * 2);
    ushort* h       = (ushort*)alloc((size_t)NN * DD * 2);
    if (off > ws_size) return;

    hipMemsetAsync(d_ws, 0, zero_bytes, stream);

    dim3 wgrid(576, 2);
    k_build_w2<<<wgrid, 256, 0, stream>>>(basis0, comp0, root0, basis1, comp1, root1, wT0, wT1);
    k_cvt_bf16<<<6250, 256, 0, stream>>>(x, xb, NN * DD / 4);
    k_hist<<<3125, 256, 0, stream>>>(ei, et, deg_dr);
    k_scan1<<<196, 256, 0, stream>>>(deg_dr, bsum, NN);
    k_scan2<<<1, 256, 0, stream>>>(bsum, 196);
    k_scan3<<<196, 256, 0, stream>>>(deg_dr, bsum, row_ptr, NN);
    k_scatter<<<3125, 256, 0, stream>>>(ei, et, row_ptr, deg_dr, cursor, ekw);

    int fblocks = (NN + RPB - 1) / RPB;   // 1563
    k_fused3<<<fblocks, 512, 0, stream>>>(xb, row_ptr, ekw, wT0, bias0, h, nullptr);
    k_fused3<<<fblocks, 512, 0, stream>>>(h, row_ptr, ekw, wT1, bias1, nullptr, out);
}

// Round 6
// 309.326 us; speedup vs baseline: 4.2880x; 1.1232x over previous
//
#include <hip/hip_runtime.h>

#define NN 50000
#define EE 800000
#define DD 128
#define RR 8
#define KSTACK 1152    // (RR+1)*DD stacked K
#define NR2 (NN * RR)  // 400000
#define RPB 32         // dst rows per fused block
#define ROWB 2304      // bytes per A-tile row (1152 bf16, no pad; XOR swizzle instead)
#define DUMP16 4608    // (RPB*ROWB)>>4 : dump slot base16 for dummy edges

typedef __attribute__((ext_vector_type(8))) short bf16x8;
typedef __attribute__((ext_vector_type(4))) float f32x4;

__device__ inline float bf2f(ushort u) {
    union { uint i; float f; } v; v.i = ((uint)u) << 16; return v.f;
}
__device__ inline ushort f2bf(float f) {
    uint b = __float_as_uint(f);
    uint r = (b + 0x7fffu + ((b >> 16) & 1u)) >> 16;
    return (ushort)r;
}

// Both layers' stacked transposed weights: wT[o][k].
__global__ void k_build_w2(const float* __restrict__ b0, const float* __restrict__ c0,
                           const float* __restrict__ r0, const float* __restrict__ b1,
                           const float* __restrict__ c1, const float* __restrict__ r1,
                           ushort* __restrict__ w0, ushort* __restrict__ w1) {
    int idx = blockIdx.x * 256 + threadIdx.x;
    if (idx >= DD * KSTACK) return;
    const float* basis = blockIdx.y ? b1 : b0;
    const float* comp  = blockIdx.y ? c1 : c0;
    const float* root  = blockIdx.y ? r1 : r0;
    ushort* wT         = blockIdx.y ? w1 : w0;
    int o = idx / KSTACK;
    int k = idx % KSTACK;
    float val;
    if (k < RR * DD) {
        int r = k >> 7, i = k & 127;
        float s = 0.f;
        #pragma unroll
        for (int b = 0; b < 8; ++b) s += comp[r * 8 + b] * basis[(b * 128 + i) * 128 + o];
        val = s;
    } else {
        val = root[(k - RR * DD) * 128 + o];
    }
    wT[(size_t)o * KSTACK + k] = f2bf(val);
}

__global__ void k_cvt_bf16(const float* __restrict__ x, ushort* __restrict__ xb, int n4) {
    int i = blockIdx.x * 256 + threadIdx.x;
    if (i < n4) {
        float4 v = ((const float4*)x)[i];
        uint2 p;
        p.x = (uint)f2bf(v.x) | ((uint)f2bf(v.y) << 16);
        p.y = (uint)f2bf(v.z) | ((uint)f2bf(v.w) << 16);
        ((uint2*)xb)[i] = p;
    }
}

__global__ void k_hist(const int* __restrict__ ei, const int* __restrict__ et,
                       int* __restrict__ deg_dr) {
    int e = blockIdx.x * 256 + threadIdx.x;
    if (e < EE) atomicAdd(&deg_dr[ei[EE + e] * RR + et[e]], 1);
}

__device__ inline int rowdeg(const int* __restrict__ deg_dr, int n) {
    int4 a = ((const int4*)deg_dr)[2 * n];
    int4 b = ((const int4*)deg_dr)[2 * n + 1];
    return a.x + a.y + a.z + a.w + b.x + b.y + b.z + b.w;
}

__global__ void k_scan1(const int* __restrict__ deg_dr, int* __restrict__ bsum, int n) {
    __shared__ int s[256];
    int t = threadIdx.x;
    int i = blockIdx.x * 256 + t;
    s[t] = (i < n) ? rowdeg(deg_dr, i) : 0;
    __syncthreads();
    for (int o = 128; o > 0; o >>= 1) {
        if (t < o) s[t] += s[t + o];
        __syncthreads();
    }
    if (t == 0) bsum[blockIdx.x] = s[0];
}

__global__ void k_scan2(int* __restrict__ bsum, int nb) {
    __shared__ int s[256];
    int t = threadIdx.x;
    int v = (t < nb) ? bsum[t] : 0;
    s[t] = v;
    __syncthreads();
    for (int o = 1; o < 256; o <<= 1) {
        int u = (t >= o) ? s[t - o] : 0;
        __syncthreads();
        s[t] += u;
        __syncthreads();
    }
    if (t < nb) bsum[t] = s[t] - v;   // exclusive
}

__global__ void k_scan3(const int* __restrict__ deg_dr, const int* __restrict__ boff,
                        int* __restrict__ ptr, int n) {
    __shared__ int s[256];
    int t = threadIdx.x;
    int i = blockIdx.x * 256 + t;
    int v = (i < n) ? rowdeg(deg_dr, i) : 0;
    s[t] = v;
    __syncthreads();
    for (int o = 1; o < 256; o <<= 1) {
        int u = (t >= o) ? s[t - o] : 0;
        __syncthreads();
        s[t] += u;
        __syncthreads();
    }
    if (i < n) ptr[i + 1] = boff[blockIdx.x] + s[t];
    if (i == 0) ptr[0] = 0;
}

// Per edge at (dst,rel)-sorted position:
//   ekw.x = (base16<<19) | ((lrow&7)<<16) | src,  base16 = (lrow*ROWB + rel*256)>>4
//   ekw.y = 1/deg(dst,rel)
__global__ void k_scatter(const int* __restrict__ ei, const int* __restrict__ et,
                          const int* __restrict__ row_ptr, const int* __restrict__ deg_dr,
                          int* __restrict__ cursor, int2* __restrict__ ekw) {
    int e = blockIdx.x * 256 + threadIdx.x;
    if (e < EE) {
        int s = ei[e], d = ei[EE + e], t = et[e];
        int4 a = ((const int4*)deg_dr)[2 * d];
        int4 b = ((const int4*)deg_dr)[2 * d + 1];
        int pre = 0;
        pre += (t > 0) ? a.x : 0; pre += (t > 1) ? a.y : 0;
        pre += (t > 2) ? a.z : 0; pre += (t > 3) ? a.w : 0;
        pre += (t > 4) ? b.x : 0; pre += (t > 5) ? b.y : 0;
        pre += (t > 6) ? b.z : 0;
        int deg = (t == 0) ? a.x : (t == 1) ? a.y : (t == 2) ? a.z : (t == 3) ? a.w
                : (t == 4) ? b.x : (t == 5) ? b.y : (t == 6) ? b.z : b.w;
        int p = row_ptr[d] + pre + atomicAdd(&cursor[d * RR + t], 1);
        int lrow = d & (RPB - 1);
        int base16 = lrow * (ROWB >> 4) + t * 16;
        int2 pk;
        pk.x = (base16 << 19) | ((lrow & 7) << 16) | s;
        pk.y = __float_as_int(1.f / (float)deg);
        ekw[p] = pk;
    }
}

// Fused layer. Block = 32 dst rows, 512 threads (8 waves), 74KB LDS -> 2 blocks/CU.
// Phase 1: each wave owns 4 rows as ONE flat (dst,rel)-sorted edge stream;
//          2-deep software pipeline in chunks of 8 (16 gathers in flight);
//          register run-accumulation, unconditional overwrite-flush to the bf16
//          A-tile (last write of a (row,rel)-run holds the full f32 sum).
//          Tail edges are branch-free dummies (w=0 -> dump slot).
// Phase 2: 36 K-step MFMA GEMM [32x1152]@[1152x128]; A from XOR-swizzled LDS,
//          B streamed from L2-resident wT; fused bias (+ReLU).
__global__ void __launch_bounds__(512, 4) k_fused4(
        const ushort* __restrict__ in, const int* __restrict__ rp,
        const int2* __restrict__ ekw, const ushort* __restrict__ BT,
        const float* __restrict__ bias, ushort* __restrict__ hout,
        float* __restrict__ fout) {
    __shared__ uint4 at4[(RPB * ROWB + 256) / 16];   // 73,984 B
    char* atb = (char*)at4;
    int tid = threadIdx.x, wid = tid >> 6, lane = tid & 63;
    int blockrow = blockIdx.x * RPB;
    uint lane4 = (uint)lane << 2;

    {
        uint4 z = {0u, 0u, 0u, 0u};
        for (int i = tid; i < (RPB * ROWB + 256) / 16; i += 512) at4[i] = z;
    }
    __syncthreads();

    const ushort* inl = in + (lane << 1);

    // self (root) slots, coalesced reads
    #pragma unroll
    for (int rr = 0; rr < 4; ++rr) {
        int lr = (wid << 2) + rr;
        int n = blockrow + lr;
        if (n < NN) {
            uint su = *(const uint*)(inl + (size_t)n * DD);
            uint off = (uint)(lr * ROWB + 2048) + (lane4 ^ ((uint)(lr & 7) << 4));
            *(uint*)(atb + off) = su;
        }
    }

    // flat edge range for this wave's 4 rows
    int n0 = blockrow + (wid << 2);
    int i0 = n0 < NN ? n0 : NN;
    int i1 = n0 + 4 < NN ? n0 + 4 : NN;
    int p    = __builtin_amdgcn_readfirstlane(rp[i0]);
    int pend = __builtin_amdgcn_readfirstlane(rp[i1]);
    int nb = pend - p;

    const int U = 8;
    int2 kA[U], kB[U];
    uint gA[U], gB[U];
    float a0 = 0.f, a1 = 0.f;
    uint prev = 0xFFFFFFFFu;

    auto loadc = [&](int2* kb, uint* gb, int base) {
        #pragma unroll
        for (int j = 0; j < U; ++j) {
            int pe = base + j;
            bool dummy = pe >= pend;
            pe = dummy ? (pend - 1) : pe;
            int2 e = ekw[pe];
            if (dummy) { e.x = (int)((uint)DUMP16 << 19); e.y = 0; }
            kb[j] = e;
        }
        #pragma unroll
        for (int j = 0; j < U; ++j)
            gb[j] = *(const uint*)(inl + ((size_t)(kb[j].x & 0xFFFF)) * DD);
    };
    auto proc = [&](int2* kb, uint* gb) {
        #pragma unroll
        for (int j = 0; j < U; ++j) {
            uint ex = (uint)kb[j].x;
            float w = __int_as_float(kb[j].y);
            uint off = ((ex >> 19) << 4) + (lane4 ^ ((ex >> 12) & 0x70u));
            bool same = (off == prev);
            a0 = same ? a0 : 0.f;
            a1 = same ? a1 : 0.f;
            uint g = gb[j];
            a0 += w * bf2f((ushort)(g & 0xFFFFu));
            a1 += w * bf2f((ushort)(g >> 16));
            uint pk;
            asm("v_cvt_pk_bf16_f32 %0, %1, %2" : "=v"(pk) : "v"(a0), "v"(a1));
            *(uint*)(atb + off) = pk;
            prev = off;
        }
    };

    if (nb > 0) {
        int nch = (nb + U - 1) / U;
        loadc(kA, gA, p);
        int i = 1;
        for (; i + 1 < nch; i += 2) {
            loadc(kB, gB, p + i * U);
            proc(kA, gA);
            loadc(kA, gA, p + (i + 1) * U);
            proc(kB, gB);
        }
        if (i < nch) {
            loadc(kB, gB, p + i * U);
            proc(kA, gA);
            proc(kB, gB);
        } else {
            proc(kA, gA);
        }
    }
    __syncthreads();

    // Phase 2: wave wid -> cols [wid*16, wid*16+16), rows 0..31 (2 fragments).
    int rlo = lane & 15, q = lane >> 4;
    int colbase = wid << 4;
    uint x7 = (uint)(rlo & 7) << 4;
    const char* arow0 = atb + rlo * ROWB;
    const char* arow1 = atb + (rlo + 16) * ROWB;
    const ushort* bp = BT + (size_t)(colbase + rlo) * KSTACK + (q << 3);
    f32x4 c0 = {0.f, 0.f, 0.f, 0.f}, c1 = {0.f, 0.f, 0.f, 0.f};
    #pragma unroll 4
    for (int kk = 0; kk < KSTACK / 32; ++kk) {
        uint loff = (uint)(kk * 64 + q * 16) ^ x7;
        bf16x8 b  = *(const bf16x8*)(bp + kk * 32);
        bf16x8 a0f = *(const bf16x8*)(arow0 + loff);
        bf16x8 a1f = *(const bf16x8*)(arow1 + loff);
        c0 = __builtin_amdgcn_mfma_f32_16x16x32_bf16(a0f, b, c0, 0, 0, 0);
        c1 = __builtin_amdgcn_mfma_f32_16x16x32_bf16(a1f, b, c1, 0, 0, 0);
    }
    int col = colbase + rlo;
    float bv = bias[col];
    int rowoff = q << 2;
    #pragma unroll
    for (int f = 0; f < 2; ++f) {
        f32x4 cv = f ? c1 : c0;
        #pragma unroll
        for (int rg = 0; rg < 4; ++rg) {
            int row = blockrow + f * 16 + rowoff + rg;
            if (row < NN) {
                float v = cv[rg] + bv;
                if (hout) {
                    v = fmaxf(v, 0.f);
                    hout[(size_t)row * DD + col] = f2bf(v);
                } else {
                    fout[(size_t)row * DD + col] = v;
                }
            }
        }
    }
}

extern "C" void kernel_launch(void* const* d_in, const int* in_sizes, int n_in,
                              void* d_out, int out_size, void* d_ws, size_t ws_size,
                              hipStream_t stream) {
    const float* x      = (const float*)d_in[0];
    const int*   ei     = (const int*)d_in[1];
    const int*   et     = (const int*)d_in[2];
    const float* basis0 = (const float*)d_in[3];
    const float* comp0  = (const float*)d_in[4];
    const float* root0  = (const float*)d_in[5];
    const float* bias0  = (const float*)d_in[6];
    const float* basis1 = (const float*)d_in[7];
    const float* comp1  = (const float*)d_in[8];
    const float* root1  = (const float*)d_in[9];
    const float* bias1  = (const float*)d_in[10];
    float* out = (float*)d_out;

    char* ws = (char*)d_ws;
    size_t off = 0;
    auto alloc = [&](size_t bytes) -> void* {
        void* p = ws + off;
        off += (bytes + 255) & ~(size_t)255;
        return p;
    };
    int*    deg_dr  = (int*)alloc((size_t)NR2 * 4);
    int*    cursor  = (int*)alloc((size_t)NR2 * 4);
    size_t zero_bytes = off;
    int*    row_ptr = (int*)alloc((size_t)(NN + 1) * 4);
    int*    bsum    = (int*)alloc(256 * 4);
    int2*   ekw     = (int2*)alloc((size_t)EE * 8);
    ushort* wT0     = (ushort*)alloc((size_t)DD * KSTACK * 2);
    ushort* wT1     = (ushort*)alloc((size_t)DD * KSTACK * 2);
    ushort* xb      = (ushort*)alloc((size_t)NN * DD * 2);
    ushort* h       = (ushort*)alloc((size_t)NN * DD * 2);
    if (off > ws_size) return;

    hipMemsetAsync(d_ws, 0, zero_bytes, stream);

    dim3 wgrid(576, 2);
    k_build_w2<<<wgrid, 256, 0, stream>>>(basis0, comp0, root0, basis1, comp1, root1, wT0, wT1);
    k_cvt_bf16<<<6250, 256, 0, stream>>>(x, xb, NN * DD / 4);
    k_hist<<<3125, 256, 0, stream>>>(ei, et, deg_dr);
    k_scan1<<<196, 256, 0, stream>>>(deg_dr, bsum, NN);
    k_scan2<<<1, 256, 0, stream>>>(bsum, 196);
    k_scan3<<<196, 256, 0, stream>>>(deg_dr, bsum, row_ptr, NN);
    k_scatter<<<3125, 256, 0, stream>>>(ei, et, row_ptr, deg_dr, cursor, ekw);

    int fblocks = (NN + RPB - 1) / RPB;   // 1563
    k_fused4<<<fblocks, 512, 0, stream>>>(xb, row_ptr, ekw, wT0, bias0, h, nullptr);
    k_fused4<<<fblocks, 512, 0, stream>>>(h, row_ptr, ekw, wT1, bias1, nullptr, out);
}